// Round 1
// baseline (589.509 us; speedup 1.0000x reference)
//
#include <hip/hip_runtime.h>

#define HWDIM 1024            // 32*32
#define DDIM 256
#define KCODES 1024
#define NROWS 32768           // 32 * 1024
#define BSTRIDE (DDIM * HWDIM) // per-batch stride in input = 262144

// ---- ws layout (float units unless noted) ----
// wT   : [0, 262144)          transposed codebook, d-major [256][1024]
// rr   : [262144, 294912)     ||x_n||^2, numpy-pairwise fp32
// ss   : [294912, 295936)     ||e_k||^2, numpy-pairwise fp32
// idx  : [295936, 328704)     argmin index per row (uint32)
// hist : [328704, 329728)     code histogram (int32)
// loss : byte offset 1318912  (double)

// ---- out layout (floats) ----
// [0] loss ; [1, 8388609) quantized_st ; [8388609] perplexity ;
// [8388610, 41943042) encodings one-hot

// numpy-exact pairwise sum of squares over 128 elements (np pairwise block)
__device__ __forceinline__ float pair128_sq(const float* __restrict__ p, int stride) {
  float a[8];
#pragma unroll
  for (int j = 0; j < 8; ++j) { float v = p[j * stride]; a[j] = __fmul_rn(v, v); }
  for (int i = 8; i < 128; i += 8) {
#pragma unroll
    for (int j = 0; j < 8; ++j) {
      float v = p[(i + j) * stride];
      a[j] = __fadd_rn(a[j], __fmul_rn(v, v));
    }
  }
  float s01 = __fadd_rn(a[0], a[1]), s23 = __fadd_rn(a[2], a[3]);
  float s45 = __fadd_rn(a[4], a[5]), s67 = __fadd_rn(a[6], a[7]);
  return __fadd_rn(__fadd_rn(s01, s23), __fadd_rn(s45, s67));
}

__global__ void k_init(int* __restrict__ hist, double* __restrict__ loss) {
  int t = blockIdx.x * blockDim.x + threadIdx.x;
  if (t < KCODES) hist[t] = 0;
  if (t == 0) *loss = 0.0;
}

// ||x_n||^2 — row n reads input with stride HWDIM (coalesced across lanes)
__global__ void k_rownorm(const float* __restrict__ in, float* __restrict__ rr) {
  int n = blockIdx.x * blockDim.x + threadIdx.x;
  if (n >= NROWS) return;
  const float* p = in + (n >> 10) * BSTRIDE + (n & 1023);
  rr[n] = __fadd_rn(pair128_sq(p, HWDIM), pair128_sq(p + 128 * HWDIM, HWDIM));
}

// ||e_k||^2 — contiguous codebook row
__global__ void k_codenorm(const float* __restrict__ w, float* __restrict__ ss) {
  int k = blockIdx.x * blockDim.x + threadIdx.x;
  if (k >= KCODES) return;
  const float* p = w + k * DDIM;
  ss[k] = __fadd_rn(pair128_sq(p, 1), pair128_sq(p + 128, 1));
}

// transpose codebook to d-major wT[d][k]
__global__ void k_transpose(const float* __restrict__ w, float* __restrict__ wT) {
  int t = blockIdx.x * blockDim.x + threadIdx.x;  // 262144
  int k = t & 1023, d = t >> 10;
  wT[t] = w[k * DDIM + d];
}

// zero encodings (+perplexity slot, tail)
__global__ void k_zero_enc(float4* __restrict__ p4, float* __restrict__ tail) {
  int t = blockIdx.x * blockDim.x + threadIdx.x;  // 524288 threads
#pragma unroll
  for (int i = 0; i < 16; ++i) p4[t + i * 524288] = make_float4(0.f, 0.f, 0.f, 0.f);
  if (t == 0) { tail[0] = 0.f; tail[1] = 0.f; }
}

// main distance + argmin kernel: 64 rows x all 1024 codes per block
#define DC 64
__global__ __launch_bounds__(256) void k_argmin(
    const float* __restrict__ in, const float* __restrict__ wT,
    const float* __restrict__ rr, const float* __restrict__ ss,
    unsigned* __restrict__ idx, int* __restrict__ hist) {
  __shared__ float xs[DC][64];     // [d][row] 16 KB
  __shared__ float wsh[DC][128];   // [d][code] 32 KB
  __shared__ unsigned long long best[64];

  const int t = threadIdx.x;
  const int n0 = blockIdx.x * 64;
  const int b = n0 >> 10;
  const int hw0 = n0 & 1023;
  const float* xbase = in + b * BSTRIDE + hw0;
  const int tr = t & 15, tc = t >> 4;            // 16 x 16 threads; micro 4 rows x 8 codes

  if (t < 64) best[t] = 0xFFFFFFFFFFFFFFFFull;

  float rv[4];
#pragma unroll
  for (int i = 0; i < 4; ++i) rv[i] = rr[n0 + tr * 4 + i];

  const int xr4 = (t & 15) * 4, xdl = t >> 4;    // x loader: 16 rows-of-4 x 16 d
  const int wk4 = (t & 31) * 4, wdl = t >> 5;    // w loader: 32 codes-of-4 x 8 d

  for (int kc = 0; kc < KCODES; kc += 128) {
    float acc[4][8];
#pragma unroll
    for (int i = 0; i < 4; ++i)
#pragma unroll
      for (int j = 0; j < 8; ++j) acc[i][j] = 0.f;

    for (int dc = 0; dc < DDIM; dc += DC) {
      __syncthreads();
#pragma unroll
      for (int m = 0; m < 4; ++m) {
        int d = xdl + 16 * m;
        *(float4*)&xs[d][xr4] = *(const float4*)(xbase + (dc + d) * HWDIM + xr4);
      }
#pragma unroll
      for (int m = 0; m < 8; ++m) {
        int d = wdl + 8 * m;
        *(float4*)&wsh[d][wk4] = *(const float4*)(wT + (dc + d) * KCODES + kc + wk4);
      }
      __syncthreads();
#pragma unroll 8
      for (int d = 0; d < DC; ++d) {
        float4 xv = *(const float4*)&xs[d][tr * 4];
        float4 wa = *(const float4*)&wsh[d][tc * 8];
        float4 wb = *(const float4*)&wsh[d][tc * 8 + 4];
        float xarr[4] = {xv.x, xv.y, xv.z, xv.w};
        float warr[8] = {wa.x, wa.y, wa.z, wa.w, wb.x, wb.y, wb.z, wb.w};
#pragma unroll
        for (int i = 0; i < 4; ++i)
#pragma unroll
          for (int j = 0; j < 8; ++j) acc[i][j] = fmaf(xarr[i], warr[j], acc[i][j]);
      }
    }

    // fold distances for this 128-code chunk
    float sv[8];
#pragma unroll
    for (int j = 0; j < 8; ++j) sv[j] = ss[kc + tc * 8 + j];
#pragma unroll
    for (int i = 0; i < 4; ++i) {
      float bd = 3.402823466e+38f;
      int bk = 0;
#pragma unroll
      for (int j = 0; j < 8; ++j) {
        float tv = __fadd_rn(rv[i], sv[j]);            // fl(r + s)  (numpy broadcast add)
        float dist = fmaf(-2.0f, acc[i][j], tv);       // == fl((r+s) - 2m): 2m exact
        if (dist < bd) { bd = dist; bk = j; }          // ascending j => first-min tie-break
      }
      unsigned ub = __float_as_uint(bd);
      ub = (ub & 0x80000000u) ? ~ub : (ub | 0x80000000u);  // monotone map
      unsigned long long key = ((unsigned long long)ub << 32) |
                               (unsigned)(kc + tc * 8 + bk);
      atomicMin(&best[tr * 4 + i], key);               // lowest dist, then lowest k
    }
  }

  __syncthreads();
  if (t < 64) {
    unsigned k = (unsigned)(best[t] & 0xFFFFFFFFull);
    idx[n0 + t] = k;
    atomicAdd(&hist[k], 1);
  }
}

// quantized_st output + squared-error sum
__global__ void k_quant(const float* __restrict__ in, const float* __restrict__ w,
                        const unsigned* __restrict__ idx, float* __restrict__ outq,
                        double* __restrict__ loss) {
  __shared__ double red[256];
  const int t0 = blockIdx.x * blockDim.x + threadIdx.x;  // 262144 threads
  double lsum = 0.0;
#pragma unroll 4
  for (int i = 0; i < 32; ++i) {
    int e = t0 + i * 262144;
    int b = e >> 18;
    int rem = e & 262143;
    int d = rem >> 10;
    int hw = rem & 1023;
    unsigned k = idx[(b << 10) + hw];
    float x = in[e];
    float wv = w[k * DDIM + d];
    float diff = __fsub_rn(wv, x);                 // fl(quantized - x)
    outq[e] = __fadd_rn(x, diff);                  // fl(x + fl(q - x)) == np exactly
    lsum += (double)diff * (double)diff;
  }
  red[threadIdx.x] = lsum;
  __syncthreads();
  for (int s = 128; s > 0; s >>= 1) {
    if (threadIdx.x < s) red[threadIdx.x] += red[threadIdx.x + s];
    __syncthreads();
  }
  if (threadIdx.x == 0) atomicAdd(loss, red[0]);
}

__global__ void k_scatter(const unsigned* __restrict__ idx, float* __restrict__ enc) {
  int n = blockIdx.x * blockDim.x + threadIdx.x;
  if (n < NROWS) enc[n * KCODES + idx[n]] = 1.0f;
}

__global__ void k_final(const int* __restrict__ hist, const double* __restrict__ loss,
                        float* __restrict__ out) {
  __shared__ double red[256];
  int t = threadIdx.x;
  double s = 0.0;
  for (int i = t; i < KCODES; i += 256) {
    double p = (double)hist[i] * (1.0 / 32768.0);
    s += p * log(p + 1e-10);
  }
  red[t] = s;
  __syncthreads();
  for (int st = 128; st > 0; st >>= 1) {
    if (t < st) red[t] += red[t + st];
    __syncthreads();
  }
  if (t == 0) {
    out[8388609] = (float)exp(-red[0]);
    double m = *loss / 8388608.0;
    out[0] = (float)(1.25 * m);   // q_latent + 0.25 * e_latent, identical values
  }
}

extern "C" void kernel_launch(void* const* d_in, const int* in_sizes, int n_in,
                              void* d_out, int out_size, void* d_ws, size_t ws_size,
                              hipStream_t stream) {
  const float* in = (const float*)d_in[0];   // [32,256,32,32]
  const float* w  = (const float*)d_in[1];   // [1024,256]
  float* out = (float*)d_out;

  float* wsf  = (float*)d_ws;
  float* wT   = wsf;
  float* rr   = wsf + 262144;
  float* sspt = wsf + 294912;
  unsigned* idx = (unsigned*)(wsf + 295936);
  int* hist   = (int*)(wsf + 328704);
  double* loss = (double*)((char*)d_ws + 1318912);

  k_init<<<dim3(4), dim3(256), 0, stream>>>(hist, loss);
  k_codenorm<<<dim3(4), dim3(256), 0, stream>>>(w, sspt);
  k_rownorm<<<dim3(128), dim3(256), 0, stream>>>(in, rr);
  k_transpose<<<dim3(1024), dim3(256), 0, stream>>>(w, wT);
  k_zero_enc<<<dim3(2048), dim3(256), 0, stream>>>((float4*)(out + 8388608),
                                                   out + 41943040);
  k_argmin<<<dim3(512), dim3(256), 0, stream>>>(in, wT, rr, sspt, idx, hist);
  k_scatter<<<dim3(128), dim3(256), 0, stream>>>(idx, out + 8388610);
  k_quant<<<dim3(1024), dim3(256), 0, stream>>>(in, w, idx, out + 1, loss);
  k_final<<<dim3(1), dim3(256), 0, stream>>>(hist, loss, out);
}

// Round 2
// 489.922 us; speedup vs baseline: 1.2033x; 1.2033x over previous
//
#include <hip/hip_runtime.h>

#define HWDIM 1024             // 32*32
#define DDIM 256
#define KCODES 1024
#define NROWS 32768            // 32 * 1024
#define BSTRIDE (DDIM * HWDIM) // per-batch stride in input = 262144

// ---- ws layout (float units unless noted) ----
// wT    : [0, 262144)           transposed codebook, d-major [256][1024]
// rr    : [262144, 294912)      ||x_n||^2, numpy-pairwise fp32
// ss    : [294912, 295936)      ||e_k||^2, numpy-pairwise fp32
// gbest : [295936, 361472)      packed (ordered_dist<<32 | k) u64 per row
// hist  : [361472, 362496)      code histogram (int32)
// loss  : byte offset 1449984   (double)

// ---- out layout (floats) ----
// [0] loss ; [1, 8388609) quantized_st ; [8388609] perplexity ;
// [8388610, 41943042) encodings one-hot

// numpy-exact pairwise sum of squares over 128 elements (np pairwise block)
__device__ __forceinline__ float pair128_sq(const float* __restrict__ p, int stride) {
  float a[8];
#pragma unroll
  for (int j = 0; j < 8; ++j) { float v = p[j * stride]; a[j] = __fmul_rn(v, v); }
  for (int i = 8; i < 128; i += 8) {
#pragma unroll
    for (int j = 0; j < 8; ++j) {
      float v = p[(i + j) * stride];
      a[j] = __fadd_rn(a[j], __fmul_rn(v, v));
    }
  }
  float s01 = __fadd_rn(a[0], a[1]), s23 = __fadd_rn(a[2], a[3]);
  float s45 = __fadd_rn(a[4], a[5]), s67 = __fadd_rn(a[6], a[7]);
  return __fadd_rn(__fadd_rn(s01, s23), __fadd_rn(s45, s67));
}

// fused prep: transpose codebook, init gbest/hist/loss, codebook norms
__global__ void k_prep(const float* __restrict__ w, float* __restrict__ wT,
                       float* __restrict__ ss, unsigned long long* __restrict__ gbest,
                       int* __restrict__ hist, double* __restrict__ loss) {
  int g = blockIdx.x * 256 + threadIdx.x;   // 262144 threads
  {
    int k = g & 1023, d = g >> 10;
    wT[g] = w[k * DDIM + d];
  }
  if (g < NROWS) gbest[g] = 0xFFFFFFFFFFFFFFFFull;
  if (g < KCODES) {
    hist[g] = 0;
    const float* p = w + g * DDIM;
    ss[g] = __fadd_rn(pair128_sq(p, 1), pair128_sq(p + 128, 1));
  }
  if (g == 0) *loss = 0.0;
}

// ||x_n||^2 — row n reads input with stride HWDIM (coalesced across lanes)
__global__ void k_rownorm(const float* __restrict__ in, float* __restrict__ rr) {
  int n = blockIdx.x * blockDim.x + threadIdx.x;
  if (n >= NROWS) return;
  const float* p = in + (n >> 10) * BSTRIDE + (n & 1023);
  rr[n] = __fadd_rn(pair128_sq(p, HWDIM), pair128_sq(p + 128 * HWDIM, HWDIM));
}

// main distance + argmin: 128 rows x 128 codes per block, 8x8 micro-tile.
// Thread (R=t>>4, C=t&15) covers rows {R*4+i, 64+R*4+i}, codes {C*4+j, 64+C*4+j}
// so all LDS reads are <=2-way bank conflicts (free on gfx950).
#define DCHUNK 32
__global__ __launch_bounds__(256) void k_argmin(
    const float* __restrict__ in, const float* __restrict__ wT,
    const float* __restrict__ rr, const float* __restrict__ ss,
    unsigned long long* __restrict__ gbest) {
  __shared__ __align__(16) float xs[DCHUNK][128];   // 16 KB
  __shared__ __align__(16) float wsh[DCHUNK][128];  // 16 KB
  __shared__ unsigned long long best[128];          // 1 KB

  const int t = threadIdx.x;
  const int n0 = blockIdx.x * 128;    // 128-aligned -> same batch (1024 rows/batch)
  const int kc = blockIdx.y * 128;
  const float* xbase = in + (n0 >> 10) * BSTRIDE + (n0 & 1023);
  const int R = t >> 4, C = t & 15;

  if (t < 128) best[t] = 0xFFFFFFFFFFFFFFFFull;

  float acc[8][8];
#pragma unroll
  for (int i = 0; i < 8; ++i)
#pragma unroll
    for (int j = 0; j < 8; ++j) acc[i][j] = 0.f;

  for (int dc = 0; dc < DDIM; dc += DCHUNK) {
    __syncthreads();
#pragma unroll
    for (int m = 0; m < 4; ++m) {
      int u = t + m * 256;            // float4 index, 1024 total
      int d = u >> 5, c4 = u & 31;    // 32 float4 per d-row
      *(float4*)&xs[d][c4 * 4] =
          *(const float4*)(xbase + (dc + d) * HWDIM + c4 * 4);
      *(float4*)&wsh[d][c4 * 4] =
          *(const float4*)(wT + (dc + d) * KCODES + kc + c4 * 4);
    }
    __syncthreads();
#pragma unroll 8
    for (int d = 0; d < DCHUNK; ++d) {
      float4 x0 = *(const float4*)&xs[d][R * 4];
      float4 x1 = *(const float4*)&xs[d][64 + R * 4];
      float4 w0 = *(const float4*)&wsh[d][C * 4];
      float4 w1 = *(const float4*)&wsh[d][64 + C * 4];
      float xa[8] = {x0.x, x0.y, x0.z, x0.w, x1.x, x1.y, x1.z, x1.w};
      float wa[8] = {w0.x, w0.y, w0.z, w0.w, w1.x, w1.y, w1.z, w1.w};
#pragma unroll
      for (int i = 0; i < 8; ++i)
#pragma unroll
        for (int j = 0; j < 8; ++j) acc[i][j] = fmaf(xa[i], wa[j], acc[i][j]);
    }
  }

  // fold distances: dist = fl(fl(r+s) - 2m), numpy-exact (2m exact)
  float rv[8], sv[8];
#pragma unroll
  for (int i = 0; i < 4; ++i) {
    rv[i] = rr[n0 + R * 4 + i];
    rv[4 + i] = rr[n0 + 64 + R * 4 + i];
    sv[i] = ss[kc + C * 4 + i];
    sv[4 + i] = ss[kc + 64 + C * 4 + i];
  }
#pragma unroll
  for (int i = 0; i < 8; ++i) {
    float bd = 3.402823466e+38f;
    int bk = 0;
#pragma unroll
    for (int j = 0; j < 8; ++j) {   // j ascending => global k ascending (tie->low k)
      float dist = fmaf(-2.0f, acc[i][j], __fadd_rn(rv[i], sv[j]));
      if (dist < bd) { bd = dist; bk = j; }
    }
    int kloc = kc + ((bk < 4) ? (C * 4 + bk) : (64 + C * 4 + (bk - 4)));
    unsigned ub = __float_as_uint(bd);
    ub = (ub & 0x80000000u) ? ~ub : (ub | 0x80000000u);  // monotone map
    unsigned long long key = ((unsigned long long)ub << 32) | (unsigned)kloc;
    int row = (i < 4) ? (R * 4 + i) : (64 + R * 4 + (i - 4));
    atomicMin(&best[row], key);
  }

  __syncthreads();
  if (t < 128) atomicMin(&gbest[n0 + t], best[t]);
}

// one-hot encodings write (including zeros) + histogram. 4 rows per block.
__global__ void k_enc(const unsigned long long* __restrict__ gbest,
                      float2* __restrict__ enc, int* __restrict__ hist) {
  __shared__ unsigned kk[4];
  const int t = threadIdx.x;
  const int r0 = blockIdx.x * 4;
  if (t < 4) {
    unsigned k = (unsigned)(gbest[r0 + t] & 0xFFFFFFFFull);
    kk[t] = k;
    atomicAdd(&hist[k], 1);
  }
  __syncthreads();
#pragma unroll
  for (int m = 0; m < 8; ++m) {
    int u = t + m * 256;            // float2 index, 2048 total (4 rows x 512)
    int r = u >> 9, c2 = u & 511;
    int k = (int)kk[r];
    float2 v;
    v.x = (c2 * 2 == k) ? 1.0f : 0.0f;
    v.y = (c2 * 2 + 1 == k) ? 1.0f : 0.0f;
    enc[(size_t)(r0 + r) * 512 + c2] = v;
  }
}

// quantized_st output + squared-error sum
__global__ void k_quant(const float* __restrict__ in, const float* __restrict__ w,
                        const unsigned long long* __restrict__ gbest,
                        float* __restrict__ outq, double* __restrict__ loss) {
  __shared__ double red[256];
  const int t0 = blockIdx.x * blockDim.x + threadIdx.x;  // 262144 threads
  double lsum = 0.0;
#pragma unroll 4
  for (int i = 0; i < 32; ++i) {
    int e = t0 + i * 262144;
    int b = e >> 18;
    int rem = e & 262143;
    int d = rem >> 10;
    int hw = rem & 1023;
    unsigned k = (unsigned)(gbest[(b << 10) + hw] & 0xFFFFFFFFull);
    float x = in[e];
    float wv = w[k * DDIM + d];
    float diff = __fsub_rn(wv, x);                 // fl(quantized - x)
    outq[e] = __fadd_rn(x, diff);                  // fl(x + fl(q - x)) == np exactly
    lsum += (double)diff * (double)diff;
  }
  red[threadIdx.x] = lsum;
  __syncthreads();
  for (int s = 128; s > 0; s >>= 1) {
    if (threadIdx.x < s) red[threadIdx.x] += red[threadIdx.x + s];
    __syncthreads();
  }
  if (threadIdx.x == 0) atomicAdd(loss, red[0]);
}

__global__ void k_final(const int* __restrict__ hist, const double* __restrict__ loss,
                        float* __restrict__ out) {
  __shared__ double red[256];
  int t = threadIdx.x;
  double s = 0.0;
  for (int i = t; i < KCODES; i += 256) {
    double p = (double)hist[i] * (1.0 / 32768.0);
    s += p * log(p + 1e-10);
  }
  red[t] = s;
  __syncthreads();
  for (int st = 128; st > 0; st >>= 1) {
    if (t < st) red[t] += red[t + st];
    __syncthreads();
  }
  if (t == 0) {
    out[8388609] = (float)exp(-red[0]);
    double m = *loss / 8388608.0;
    out[0] = (float)(1.25 * m);   // q_latent + 0.25 * e_latent, identical values
  }
}

extern "C" void kernel_launch(void* const* d_in, const int* in_sizes, int n_in,
                              void* d_out, int out_size, void* d_ws, size_t ws_size,
                              hipStream_t stream) {
  const float* in = (const float*)d_in[0];   // [32,256,32,32]
  const float* w  = (const float*)d_in[1];   // [1024,256]
  float* out = (float*)d_out;

  float* wsf = (float*)d_ws;
  float* wT  = wsf;
  float* rr  = wsf + 262144;
  float* ssp = wsf + 294912;
  unsigned long long* gbest = (unsigned long long*)(wsf + 295936);
  int* hist = (int*)(wsf + 361472);
  double* loss = (double*)((char*)d_ws + 1449984);

  k_prep<<<dim3(1024), dim3(256), 0, stream>>>(w, wT, ssp, gbest, hist, loss);
  k_rownorm<<<dim3(128), dim3(256), 0, stream>>>(in, rr);
  k_argmin<<<dim3(256, 8), dim3(256), 0, stream>>>(in, wT, rr, ssp, gbest);
  k_enc<<<dim3(8192), dim3(256), 0, stream>>>(gbest, (float2*)(out + 8388610), hist);
  k_quant<<<dim3(1024), dim3(256), 0, stream>>>(in, w, gbest, out + 1, loss);
  k_final<<<dim3(1), dim3(256), 0, stream>>>(hist, loss, out);
}